// Round 2
// baseline (5579.224 us; speedup 1.0000x reference)
//
#include <hip/hip_runtime.h>

#define VV 100000
#define BB 2048
#define TT 200
#define GG 192   // 3*C
#define PP 514
#define RPB 8    // batch rows per block (mimn_rnn)

__device__ __forceinline__ float sigmf(float x) { return 1.0f / (1.0f + expf(-x)); }
__device__ __forceinline__ float softplusf(float x) {
    return fmaxf(x, 0.0f) + log1pf(expf(-fabsf(x)));
}
__device__ __forceinline__ float wred64(float x) {
#pragma unroll
    for (int m = 32; m >= 1; m >>= 1) x += __shfl_xor(x, m, 64);
    return x;
}
__device__ __forceinline__ float dot4(float4 w, float4 a) {
    return w.x * a.x + w.y * a.y + w.z * a.z + w.w * a.w;
}

// ---------------- K0: per-vocab GI tables (bih folded into GI_item) -------------
__global__ __launch_bounds__(192) void build_tables(
    const float* __restrict__ emb,   // V x 64
    const float* __restrict__ Wih,   // 192 x 256
    const float* __restrict__ bih,   // 192
    float* __restrict__ GIi, float* __restrict__ GIc)  // V x 192 each
{
    __shared__ float sE[64 * 64];
    int tid = threadIdx.x;           // = n
    int v0 = blockIdx.x * 64;
    for (int i = tid; i < 64 * 64; i += 192) {
        int vv = i >> 6, k = i & 63;
        int gv = v0 + vv;
        sE[i] = (gv < VV) ? emb[(size_t)gv * 64 + k] : 0.0f;
    }
    __syncthreads();
    int n = tid;
    float bi = bih[n];
    {
        float4 w[16];
        const float4* wp = (const float4*)(Wih + n * 256);
#pragma unroll
        for (int q = 0; q < 16; ++q) w[q] = wp[q];
        for (int vv = 0; vv < 64; ++vv) {
            int gv = v0 + vv;
            if (gv >= VV) break;
            const float4* e = (const float4*)&sE[vv * 64];
            float acc = bi;
#pragma unroll
            for (int q = 0; q < 16; ++q) acc += dot4(w[q], e[q]);
            GIi[(size_t)gv * GG + n] = acc;
        }
    }
    {
        float4 w[16];
        const float4* wp = (const float4*)(Wih + n * 256 + 64);
#pragma unroll
        for (int q = 0; q < 16; ++q) w[q] = wp[q];
        for (int vv = 0; vv < 64; ++vv) {
            int gv = v0 + vv;
            if (gv >= VV) break;
            const float4* e = (const float4*)&sE[vv * 64];
            float acc = 0.0f;
#pragma unroll
            for (int q = 0; q < 16; ++q) acc += dot4(w[q], e[q]);
            GIc[(size_t)gv * GG + n] = acc;
        }
    }
}

// ---------------- K1: hist_sum + seq_len ----------------------------------------
__global__ __launch_bounds__(128) void hist_stats(
    const int* __restrict__ hist_item, const int* __restrict__ hist_cate,
    const float* __restrict__ mask, const float* __restrict__ emb,
    float* __restrict__ hist_sum, int* __restrict__ seqlen)
{
    int b = blockIdx.x, tid = threadIdx.x;
    const int* hidx = (tid < 64) ? hist_item : hist_cate;   // wave-uniform
    int j = tid & 63;
    float acc = 0.f;
    for (int t = 0; t < TT; ++t) {
        float m = mask[b * TT + t];
        int idx = hidx[b * TT + t];
        acc += m * emb[(size_t)idx * 64 + j];
    }
    hist_sum[(size_t)b * 128 + tid] = acc;
    if (tid < 64) {
        float s = 0.f;
        for (int t = tid; t < TT; t += 64) s += mask[b * TT + t];
        s = wred64(s);
        if (tid == 0) seqlen[b] = (int)(s + 0.5f);
    }
}

// ---------------- K2: recurrence, 512 thr, RPB=8, uniform-role layout -----------
// Redesigned to fit the 128-VGPR allocation the backend insists on (the old
// role-split held 160 persistent weight VGPRs and round-tripped ~80 dwords/
// thread/step through scratch -> 8.5 GB of HBM traffic per dispatch).
//
// Per-thread persistent weights: 72 dwords (WA[12]+WB[6] float4).
//   P1a: r,z gates rows nA0=2*(tid&63)+{0,1}, cols 24*sA..+23 (sA=tid>>6)
//   P1b: n gate  row  nB=128+(tid&63),  same 24-col slice; accR/accH split at
//        the act col-128 boundary (slice-uniform jcut, float4-aligned)
//   P3:  p = h_new @ Wp^T, 2 rows x 32 cols per thread, Wp STREAMED from L2
//        (131 KB shared by all blocks -> resident; no persistent regs)
//   GI gather: each wave loads its row's GIi/GIc slice (lanes<48, float4)
//        into regs at step top, commits summed to double-buffered LDS after
//        phase-1 compute (async-stage split; latency hidden under P1).
__global__ __attribute__((amdgpu_flat_work_group_size(512, 512),
                          amdgpu_waves_per_eu(2, 2))) void mimn_rnn(
    const int* __restrict__ hist_item, const int* __restrict__ hist_cate,
    const float* __restrict__ mask,
    const float* __restrict__ Wih,   // 192x256 (cols 128..255 = read part)
    const float* __restrict__ Whh,   // 192x64
    const float* __restrict__ bhh,   // 192
    const float* __restrict__ Wp,    // 514x64
    const float* __restrict__ bp,    // 514
    const float* __restrict__ Wo,    // 64x192
    const float* __restrict__ bo,    // 64
    const float* __restrict__ M0,    // 4x128
    const float* __restrict__ GIi, const float* __restrict__ GIc,
    const int* __restrict__ seqlen,
    float* __restrict__ last_out)    // B x 64
{
    // sU union:
    //  ph1/2: rz partials [s*1024 + r*128 + n]          (8192)
    //         i_n-read    8192  + [s*512 + r*64 + n64]  (4096)
    //         h_n         12288 + [s*512 + r*64 + n64]  (4096)
    //  ph3/4: p partials  [sP*4160 + r*520 + n]         (8320)
    __shared__ __align__(16) float sU[16384];
    __shared__ __align__(16) float sGI2[2 * RPB * 192]; // double-buffered GIi+GIc
    __shared__ __align__(16) float sAct[RPB * 192];     // [0,128)=read, [128,192)=h
    __shared__ __align__(16) float sHn[RPB * 64];       // unmasked h_new
    __shared__ float sM [RPB * 512];
    __shared__ float sBp[PP];
    __shared__ float sBhh[GG];
    __shared__ __align__(16) float sWpTail[2 * 64];     // Wp rows 512,513
    __shared__ float sMask[RPB * TT];
    __shared__ int   sHI[RPB * TT];
    __shared__ int   sHC[RPB * TT];

    const int UNR = 8192, UNH = 12288;
    const int tid = threadIdx.x;
    const int b0 = blockIdx.x * RPB;
    const int r8 = tid >> 6, lane = tid & 63;        // wave id = batch row in ph2/4

    // ---- init staged state ----
    for (int i = tid; i < RPB * 192; i += 512) sAct[i] = 0.f;
    for (int i = tid; i < RPB * 64; i += 512) sHn[i] = 0.f;
    for (int i = tid; i < RPB * 512; i += 512) sM[i] = M0[i & 511];
    for (int i = tid; i < PP; i += 512) sBp[i] = bp[i];
    if (tid < GG) sBhh[tid] = bhh[tid];
    if (tid < 128) sWpTail[tid] = Wp[512 * 64 + tid];
    for (int i = tid; i < RPB * TT; i += 512) {
        int r = i / TT, tt = i - r * TT;
        sMask[i] = mask[(size_t)(b0 + r) * TT + tt];
        sHI[i]   = hist_item[(size_t)(b0 + r) * TT + tt];
        sHC[i]   = hist_cate[(size_t)(b0 + r) * TT + tt];
    }

    // ---- hoist phase-1 weights: 18 float4 = 72 dwords per thread ----
    const int rowg2 = tid & 63, sA = tid >> 6;
    const int c0A = 24 * sA;
    const int nA0 = 2 * rowg2;          // rows nA0, nA0+1 (0..127): r,z gates
    const int nB  = 128 + rowg2;        // row 128..191: n gate
    float4 WA[12];
    float4 WB[6];
#pragma unroll
    for (int jc = 0; jc < 6; ++jc) {
        int c = c0A + 4 * jc;
        if (c < 128) {
#pragma unroll
            for (int ni = 0; ni < 2; ++ni)
                WA[ni * 6 + jc] = *(const float4*)(Wih + (nA0 + ni) * 256 + 128 + c);
            WB[jc] = *(const float4*)(Wih + nB * 256 + 128 + c);
        } else {
#pragma unroll
            for (int ni = 0; ni < 2; ++ni)
                WA[ni * 6 + jc] = *(const float4*)(Whh + (nA0 + ni) * 64 + (c - 128));
            WB[jc] = *(const float4*)(Whh + nB * 64 + (c - 128));
        }
    }
    // act col<128 boundary within this thread's 24-col slice (wave-uniform)
    const int jcut = (sA <= 4) ? 6 : ((sA == 5) ? 2 : 0);

    int ts = seqlen[b0 + r8] - 1;
    ts = ts < 0 ? 0 : (ts > TT - 1 ? TT - 1 : ts);
    __syncthreads();

    // ---- initial GI load (t = 0) into buffer 0 ----
    {
        int ri = sHI[r8 * TT], rc = sHC[r8 * TT];
        if (lane < 48) {
            float4 gi = *(const float4*)(GIi + (size_t)ri * GG + lane * 4);
            float4 gc = *(const float4*)(GIc + (size_t)rc * GG + lane * 4);
            *(float4*)&sGI2[r8 * 192 + lane * 4] =
                make_float4(gi.x + gc.x, gi.y + gc.y, gi.z + gc.z, gi.w + gc.w);
        }
    }

    for (int t = 0; t < TT; ++t) {
        // ---- GI prefetch issue for t+1 (loads in flight across phase 1) ----
        float4 gi4 = make_float4(0.f, 0.f, 0.f, 0.f);
        float4 gc4 = make_float4(0.f, 0.f, 0.f, 0.f);
        {
            int tn = (t + 1 < TT) ? t + 1 : TT - 1;
            if (lane < 48) {
                int ri = sHI[r8 * TT + tn], rc = sHC[r8 * TT + tn];
                gi4 = *(const float4*)(GIi + (size_t)ri * GG + lane * 4);
                gc4 = *(const float4*)(GIc + (size_t)rc * GG + lane * 4);
            }
        }
        // ---- phase 1a: r,z gate partials (2 rows x 24 cols) ----
        {
            float acc0[8], acc1[8];
#pragma unroll
            for (int r = 0; r < 8; ++r) { acc0[r] = 0.f; acc1[r] = 0.f; }
#pragma unroll
            for (int jc = 0; jc < 6; ++jc) {
#pragma unroll
                for (int r = 0; r < 8; ++r) {
                    float4 a = *(const float4*)&sAct[r * 192 + c0A + 4 * jc];
                    acc0[r] += dot4(WA[jc], a);
                    acc1[r] += dot4(WA[6 + jc], a);
                }
            }
#pragma unroll
            for (int r = 0; r < 8; ++r)
                *(float2*)&sU[sA * 1024 + r * 128 + nA0] = make_float2(acc0[r], acc1[r]);
        }
        // ---- phase 1b: n gate partials (1 row x 24 cols, read/h split) ----
        {
            float accR[8], accH[8];
#pragma unroll
            for (int r = 0; r < 8; ++r) { accR[r] = 0.f; accH[r] = 0.f; }
#pragma unroll
            for (int jc = 0; jc < 6; ++jc) {
                float d[8];
#pragma unroll
                for (int r = 0; r < 8; ++r)
                    d[r] = dot4(WB[jc], *(const float4*)&sAct[r * 192 + c0A + 4 * jc]);
                if (jc < jcut) {            // wave-uniform branch, static acc index
#pragma unroll
                    for (int r = 0; r < 8; ++r) accR[r] += d[r];
                } else {
#pragma unroll
                    for (int r = 0; r < 8; ++r) accH[r] += d[r];
                }
            }
#pragma unroll
            for (int r = 0; r < 8; ++r) {
                sU[UNR + sA * 512 + r * 64 + rowg2] = accR[r];
                sU[UNH + sA * 512 + r * 64 + rowg2] = accH[r];
            }
        }
        // ---- GI commit (t+1) ----
        if (lane < 48)
            *(float4*)&sGI2[((t + 1) & 1) * 1536 + r8 * 192 + lane * 4] =
                make_float4(gi4.x + gc4.x, gi4.y + gc4.y, gi4.z + gc4.z, gi4.w + gc4.w);
        __syncthreads();
        // ---- phase 2: GRU gates; commit h ----
        {
            const int r = r8;
            const float* gbuf = &sGI2[(t & 1) * 1536 + r * 192];
            float g_r = sBhh[lane] + gbuf[lane];
            float g_z = sBhh[64 + lane] + gbuf[64 + lane];
            float i_n = gbuf[128 + lane];
            float h_n = sBhh[128 + lane];
#pragma unroll
            for (int s = 0; s < 8; ++s) {
                g_r += sU[s * 1024 + r * 128 + lane];
                g_z += sU[s * 1024 + r * 128 + 64 + lane];
                i_n += sU[UNR + s * 512 + r * 64 + lane];
                h_n += sU[UNH + s * 512 + r * 64 + lane];
            }
            float rg = sigmf(g_r);
            float zg = sigmf(g_z);
            float ng = tanhf(i_n + rg * h_n);
            float h_old = sAct[r * 192 + 128 + lane];
            float hn = (1.f - zg) * ng + zg * h_old;
            float mt = sMask[r * TT + t];
            sHn[r * 64 + lane] = hn;
            sAct[r * 192 + 128 + lane] = (mt > 0.f) ? hn : h_old;
        }
        __syncthreads();
        // ---- phase 3: p partials = h_new @ Wp^T (Wp streamed from L2) ----
        {
            const int rowg = tid & 255;       // rows 2*rowg, 2*rowg+1
            const int sP = tid >> 8;          // 0..1 (wave-uniform)
            const int n0 = 2 * rowg, c0 = 32 * sP;
            float acc0[8], acc1[8];
#pragma unroll
            for (int r = 0; r < 8; ++r) { acc0[r] = 0.f; acc1[r] = 0.f; }
            const float* wp0 = Wp + n0 * 64 + c0;
#pragma unroll
            for (int jc = 0; jc < 8; ++jc) {
                float4 w0 = *(const float4*)(wp0 + 4 * jc);
                float4 w1 = *(const float4*)(wp0 + 64 + 4 * jc);
#pragma unroll
                for (int r = 0; r < 8; ++r) {
                    float4 a = *(const float4*)&sHn[r * 64 + c0 + 4 * jc];
                    acc0[r] += dot4(w0, a);
                    acc1[r] += dot4(w1, a);
                }
            }
#pragma unroll
            for (int r = 0; r < 8; ++r)
                *(float2*)&sU[sP * 4160 + r * 520 + n0] = make_float2(acc0[r], acc1[r]);
        }
        if (tid < 4) {                        // tail Wp rows 512,513 (from LDS copy)
            int hrow = tid & 1, hs = tid >> 1;
            int c0 = 32 * hs;
            float a0[8];
#pragma unroll
            for (int r = 0; r < 8; ++r) a0[r] = 0.f;
#pragma unroll
            for (int jc = 0; jc < 8; ++jc) {
                float4 w0 = *(const float4*)&sWpTail[hrow * 64 + c0 + 4 * jc];
#pragma unroll
                for (int r = 0; r < 8; ++r)
                    a0[r] += dot4(w0, *(const float4*)&sHn[r * 64 + c0 + 4 * jc]);
            }
#pragma unroll
            for (int r = 0; r < 8; ++r)
                sU[hs * 4160 + r * 520 + 512 + hrow] = a0[r];
        }
        __syncthreads();
        // ---- phase 4: NTM addressing, one wave per row ----
        {
            const int row = r8;
            const int pb = row * 520;
#define PV(n) (sU[pb + (n)] + sU[4160 + pb + (n)] + sBp[(n)])
            float kr1 = tanhf(PV(lane)),       kr2 = tanhf(PV(64 + lane));
            float beta_r = softplusf(PV(128));
            float kw1 = tanhf(PV(129 + lane)), kw2 = tanhf(PV(193 + lane));
            float beta_w = softplusf(PV(257));
            float er1 = sigmf(PV(258 + lane)), er2 = sigmf(PV(322 + lane));
            float ad1 = tanhf(PV(386 + lane)), ad2 = tanhf(PV(450 + lane));
#undef PV
            float M1[4], M2[4];
#pragma unroll
            for (int s = 0; s < 4; ++s) {
                M1[s] = sM[row * 512 + s * 128 + lane];
                M2[s] = sM[row * 512 + s * 128 + 64 + lane];
            }
            float nkr = sqrtf(wred64(kr1 * kr1 + kr2 * kr2)) + 1e-8f;
            float nkw = sqrtf(wred64(kw1 * kw1 + kw2 * kw2)) + 1e-8f;
            float Kr[4], Kw[4];
#pragma unroll
            for (int s = 0; s < 4; ++s) {
                float nM = sqrtf(wred64(M1[s] * M1[s] + M2[s] * M2[s])) + 1e-8f;
                float dr = wred64(kr1 * M1[s] + kr2 * M2[s]);
                float dw = wred64(kw1 * M1[s] + kw2 * M2[s]);
                Kr[s] = dr / (nkr * nM);
                Kw[s] = dw / (nkw * nM);
            }
            float wr_[4], ww_[4];
            {
                float mx = fmaxf(fmaxf(beta_r * Kr[0], beta_r * Kr[1]),
                                 fmaxf(beta_r * Kr[2], beta_r * Kr[3]));
                float sum = 0.f;
#pragma unroll
                for (int s = 0; s < 4; ++s) { wr_[s] = expf(beta_r * Kr[s] - mx); sum += wr_[s]; }
                float inv = 1.f / sum;
#pragma unroll
                for (int s = 0; s < 4; ++s) wr_[s] *= inv;
            }
            {
                float mx = fmaxf(fmaxf(beta_w * Kw[0], beta_w * Kw[1]),
                                 fmaxf(beta_w * Kw[2], beta_w * Kw[3]));
                float sum = 0.f;
#pragma unroll
                for (int s = 0; s < 4; ++s) { ww_[s] = expf(beta_w * Kw[s] - mx); sum += ww_[s]; }
                float inv = 1.f / sum;
#pragma unroll
                for (int s = 0; s < 4; ++s) ww_[s] *= inv;
            }
            float rn1 = 0.f, rn2 = 0.f;
#pragma unroll
            for (int s = 0; s < 4; ++s) { rn1 += wr_[s] * M1[s]; rn2 += wr_[s] * M2[s]; }
            float mt = sMask[row * TT + t];
            bool vld = mt > 0.f;
            if (vld) {
#pragma unroll
                for (int s = 0; s < 4; ++s) {
                    sM[row * 512 + s * 128 + lane]      = M1[s] * (1.f - ww_[s] * er1) + ww_[s] * ad1;
                    sM[row * 512 + s * 128 + 64 + lane] = M2[s] * (1.f - ww_[s] * er2) + ww_[s] * ad2;
                }
                sAct[row * 192 + lane]      = rn1;   // committed read
                sAct[row * 192 + 64 + lane] = rn2;
            }
            if (t == ts) {
                // out = [h_new, read_new] @ Wo^T + bo  (unmasked values)
                // stash rn1/rn2 in the *current* GI buffer (free after phase 2)
                float* stash = &sGI2[(t & 1) * 1536 + row * 192];
                stash[lane] = rn1; stash[64 + lane] = rn2;
                __asm__ volatile("s_waitcnt lgkmcnt(0)" ::: "memory");
                float acc = bo[lane];
                const float* wo = Wo + lane * GG;
                for (int k = 0; k < 64; ++k)  acc += sHn[row * 64 + k] * wo[k];
                for (int k = 0; k < 128; ++k) acc += stash[k] * wo[64 + k];
                if (!vld) acc = 0.f;
                last_out[(size_t)(b0 + row) * 64 + lane] = acc;
            }
        }
        __syncthreads();
    }
}

// ---------------- K3: final MLP head --------------------------------------------
__global__ __launch_bounds__(128) void final_mlp(
    const int* __restrict__ item, const int* __restrict__ cate,
    const float* __restrict__ emb,
    const float* __restrict__ hist_sum, const float* __restrict__ last_out,
    const float* __restrict__ fc1w, const float* __restrict__ fc1b,
    const float* __restrict__ pa1,
    const float* __restrict__ fc2w, const float* __restrict__ fc2b,
    const float* __restrict__ pa2,
    const float* __restrict__ fc3w, const float* __restrict__ fc3b,
    float* __restrict__ out)
{
    __shared__ float sX[320], sH1[200], sH2[80];
    int b = blockIdx.x, tid = threadIdx.x;
    int it = item[b], ct = cate[b];
    for (int i = tid; i < 320; i += 128) {
        float val;
        if (i < 64)       val = emb[(size_t)it * 64 + i];
        else if (i < 128) val = emb[(size_t)ct * 64 + (i - 64)];
        else if (i < 256) val = hist_sum[(size_t)b * 128 + (i - 128)];
        else              val = last_out[(size_t)b * 64 + (i - 256)];
        sX[i] = val;
    }
    __syncthreads();
    float a1 = pa1[0];
    for (int o = tid; o < 200; o += 128) {
        const float4* w = (const float4*)(fc1w + o * 320);
        float acc = fc1b[o];
#pragma unroll
        for (int q = 0; q < 80; ++q) acc += dot4(w[q], *(const float4*)&sX[q * 4]);
        sH1[o] = acc > 0.f ? acc : a1 * acc;
    }
    __syncthreads();
    float a2 = pa2[0];
    for (int o = tid; o < 80; o += 128) {
        const float4* w = (const float4*)(fc2w + o * 200);
        float acc = fc2b[o];
#pragma unroll
        for (int q = 0; q < 50; ++q) acc += dot4(w[q], *(const float4*)&sH1[q * 4]);
        sH2[o] = acc > 0.f ? acc : a2 * acc;
    }
    __syncthreads();
    if (tid < 2) {
        const float4* w = (const float4*)(fc3w + tid * 80);
        float acc = fc3b[tid];
#pragma unroll
        for (int q = 0; q < 20; ++q) acc += dot4(w[q], *(const float4*)&sH2[q * 4]);
        out[b * 2 + tid] = acc;
    }
}

extern "C" void kernel_launch(void* const* d_in, const int* in_sizes, int n_in,
                              void* d_out, int out_size, void* d_ws, size_t ws_size,
                              hipStream_t stream) {
    (void)in_sizes; (void)n_in; (void)out_size; (void)ws_size;
    const int*   item      = (const int*)d_in[0];
    const int*   cate      = (const int*)d_in[1];
    const int*   hist_item = (const int*)d_in[2];
    const int*   hist_cate = (const int*)d_in[3];
    const float* mask = (const float*)d_in[4];
    const float* emb  = (const float*)d_in[5];
    const float* Wih  = (const float*)d_in[6];
    const float* Whh  = (const float*)d_in[7];
    const float* bih  = (const float*)d_in[8];
    const float* bhh  = (const float*)d_in[9];
    const float* Wp   = (const float*)d_in[10];
    const float* bp   = (const float*)d_in[11];
    const float* Wo   = (const float*)d_in[12];
    const float* bo   = (const float*)d_in[13];
    const float* M0   = (const float*)d_in[14];
    const float* fc1w = (const float*)d_in[15];
    const float* fc1b = (const float*)d_in[16];
    const float* pa1  = (const float*)d_in[17];
    const float* fc2w = (const float*)d_in[18];
    const float* fc2b = (const float*)d_in[19];
    const float* pa2  = (const float*)d_in[20];
    const float* fc3w = (const float*)d_in[21];
    const float* fc3b = (const float*)d_in[22];

    float* GIi = (float*)d_ws;                                   // V*192 f32
    float* GIc = GIi + (size_t)VV * GG;                          // V*192 f32
    float* hist_sum = GIc + (size_t)VV * GG;                     // B*128 f32
    float* last_out = hist_sum + (size_t)BB * 128;               // B*64 f32
    int* seqlen = (int*)(last_out + (size_t)BB * 64);            // B int

    build_tables<<<(VV + 63) / 64, 192, 0, stream>>>(emb, Wih, bih, GIi, GIc);
    hist_stats<<<BB, 128, 0, stream>>>(hist_item, hist_cate, mask, emb, hist_sum, seqlen);
    mimn_rnn<<<BB / RPB, 512, 0, stream>>>(hist_item, hist_cate, mask, Wih, Whh, bhh,
                                           Wp, bp, Wo, bo, M0, GIi, GIc, seqlen, last_out);
    final_mlp<<<BB, 128, 0, stream>>>(item, cate, emb, hist_sum, last_out,
                                      fc1w, fc1b, pa1, fc2w, fc2b, pa2, fc3w, fc3b,
                                      (float*)d_out);
}

// Round 3
// 5029.090 us; speedup vs baseline: 1.1094x; 1.1094x over previous
//
#include <hip/hip_runtime.h>

#define VV 100000
#define BB 2048
#define TT 200
#define GG 192   // 3*C
#define PP 514
#define RPB 8    // batch rows per block (mimn_rnn)

__device__ __forceinline__ float sigmf(float x) { return 1.0f / (1.0f + expf(-x)); }
__device__ __forceinline__ float softplusf(float x) {
    return fmaxf(x, 0.0f) + log1pf(expf(-fabsf(x)));
}
__device__ __forceinline__ float wred64(float x) {
#pragma unroll
    for (int m = 32; m >= 1; m >>= 1) x += __shfl_xor(x, m, 64);
    return x;
}
__device__ __forceinline__ float dot4(float4 w, float4 a) {
    return w.x * a.x + w.y * a.y + w.z * a.z + w.w * a.w;
}

// ---------------- K0: per-vocab GI tables (bih folded into GI_item) -------------
__global__ __launch_bounds__(192) void build_tables(
    const float* __restrict__ emb,   // V x 64
    const float* __restrict__ Wih,   // 192 x 256
    const float* __restrict__ bih,   // 192
    float* __restrict__ GIi, float* __restrict__ GIc)  // V x 192 each
{
    __shared__ float sE[64 * 64];
    int tid = threadIdx.x;           // = n
    int v0 = blockIdx.x * 64;
    for (int i = tid; i < 64 * 64; i += 192) {
        int vv = i >> 6, k = i & 63;
        int gv = v0 + vv;
        sE[i] = (gv < VV) ? emb[(size_t)gv * 64 + k] : 0.0f;
    }
    __syncthreads();
    int n = tid;
    float bi = bih[n];
    {
        float4 w[16];
        const float4* wp = (const float4*)(Wih + n * 256);
#pragma unroll
        for (int q = 0; q < 16; ++q) w[q] = wp[q];
        for (int vv = 0; vv < 64; ++vv) {
            int gv = v0 + vv;
            if (gv >= VV) break;
            const float4* e = (const float4*)&sE[vv * 64];
            float acc = bi;
#pragma unroll
            for (int q = 0; q < 16; ++q) acc += dot4(w[q], e[q]);
            GIi[(size_t)gv * GG + n] = acc;
        }
    }
    {
        float4 w[16];
        const float4* wp = (const float4*)(Wih + n * 256 + 64);
#pragma unroll
        for (int q = 0; q < 16; ++q) w[q] = wp[q];
        for (int vv = 0; vv < 64; ++vv) {
            int gv = v0 + vv;
            if (gv >= VV) break;
            const float4* e = (const float4*)&sE[vv * 64];
            float acc = 0.0f;
#pragma unroll
            for (int q = 0; q < 16; ++q) acc += dot4(w[q], e[q]);
            GIc[(size_t)gv * GG + n] = acc;
        }
    }
}

// ---------------- K1: hist_sum + seq_len ----------------------------------------
__global__ __launch_bounds__(128) void hist_stats(
    const int* __restrict__ hist_item, const int* __restrict__ hist_cate,
    const float* __restrict__ mask, const float* __restrict__ emb,
    float* __restrict__ hist_sum, int* __restrict__ seqlen)
{
    int b = blockIdx.x, tid = threadIdx.x;
    const int* hidx = (tid < 64) ? hist_item : hist_cate;   // wave-uniform
    int j = tid & 63;
    float acc = 0.f;
    for (int t = 0; t < TT; ++t) {
        float m = mask[b * TT + t];
        int idx = hidx[b * TT + t];
        acc += m * emb[(size_t)idx * 64 + j];
    }
    hist_sum[(size_t)b * 128 + tid] = acc;
    if (tid < 64) {
        float s = 0.f;
        for (int t = tid; t < TT; t += 64) s += mask[b * TT + t];
        s = wred64(s);
        if (tid == 0) seqlen[b] = (int)(s + 0.5f);
    }
}

// ---------------- K2: recurrence, 1024 thr, RPB=8, all-register weights ---------
// 1024 threads halve per-thread weight footprint vs the 512-thread layout:
//   gates: 192x192 = 36864 dw / 1024 = 36 dw;  Wp: 514x64 ~= 32 dw
//   -> ~80 persistent dwords/thread, fits the 128-VGPR allocation with NO
//   spill and NO in-loop global loads (round-2's Wp streaming cost 6.7 GB
//   of L2-miss fetch at unhidden latency; round-0's 136-dw demand spilled
//   8.5 GB of scratch traffic).
// Roles (wave-uniform):
//   waves 0-7  (rz): gate rows 2*lane,2*lane+1 (0..127 = r,z), cols 24w..24w+23
//                    W[0..11] = 2 rows x 6 float4
//   waves 8-15 (n):  gate row 128+lane, cols 24s..24s+23, W[0..5]; accR/accH
//                    split at act col 128 (jcut, wave-uniform).  Also GI
//                    gather for batch row s: lanes<48 prefetch GIi/GIc float4
//                    into W[6],W[7] (unused weight slots -> unified regalloc),
//                    commit summed into double-buffered sGI2 after compute.
//   phase 3 (all):   p = h_new @ Wp^T; row tid&511, cols 32*(tid>>9).., Wq[8]
//                    held in registers (Wp is step-invariant). Tail rows
//                    512/513 by tids 0-3 from sWpTail.
//   phases 2,4:      waves 0-7, one wave per batch row (waves 8-15 idle).
// 16 waves/CU (LDS ~122 KB -> 1 block/CU; 128 VGPR -> 16 waves/CU allowed)
// doubles latency hiding vs the 512-thread layout.
__global__ __attribute__((amdgpu_flat_work_group_size(1024, 1024),
                          amdgpu_waves_per_eu(4, 4))) void mimn_rnn(
    const int* __restrict__ hist_item, const int* __restrict__ hist_cate,
    const float* __restrict__ mask,
    const float* __restrict__ Wih,   // 192x256 (cols 128..255 = read part)
    const float* __restrict__ Whh,   // 192x64
    const float* __restrict__ bhh,   // 192
    const float* __restrict__ Wp,    // 514x64
    const float* __restrict__ bp,    // 514
    const float* __restrict__ Wo,    // 64x192
    const float* __restrict__ bo,    // 64
    const float* __restrict__ M0,    // 4x128
    const float* __restrict__ GIi, const float* __restrict__ GIc,
    const int* __restrict__ seqlen,
    float* __restrict__ last_out)    // B x 64
{
    // sU union:
    //  ph1/2: rz partials [s*1024 + r*128 + n]          (8192)
    //         i_n-read    8192  + [s*512 + r*64 + n64]  (4096)
    //         h_n         12288 + [s*512 + r*64 + n64]  (4096)
    //  ph3/4: p partials  [sP*4160 + r*520 + n]         (8320)
    __shared__ __align__(16) float sU[16384];
    __shared__ __align__(16) float sGI2[2 * RPB * 192]; // double-buffered GIi+GIc
    __shared__ __align__(16) float sAct[RPB * 192];     // [0,128)=read, [128,192)=h
    __shared__ __align__(16) float sHn[RPB * 64];       // unmasked h_new
    __shared__ float sM [RPB * 512];
    __shared__ float sBp[PP];
    __shared__ float sBhh[GG];
    __shared__ __align__(16) float sWpTail[2 * 64];     // Wp rows 512,513
    __shared__ float sMask[RPB * TT];
    __shared__ int   sHI[RPB * TT];
    __shared__ int   sHC[RPB * TT];

    const int UNR = 8192, UNH = 12288;
    const int tid = threadIdx.x;
    const int b0 = blockIdx.x * RPB;
    const int wv = tid >> 6, lane = tid & 63;
    const bool isRZ = wv < 8;
    const int sl = isRZ ? wv : (wv - 8);     // col-slice id; n-waves: also batch row
    const int c0A = 24 * sl;

    // ---- init staged state ----
    for (int i = tid; i < RPB * 192; i += 1024) sAct[i] = 0.f;
    for (int i = tid; i < RPB * 64; i += 1024) sHn[i] = 0.f;
    for (int i = tid; i < RPB * 512; i += 1024) sM[i] = M0[i & 511];
    for (int i = tid; i < PP; i += 1024) sBp[i] = bp[i];
    if (tid < GG) sBhh[tid] = bhh[tid];
    if (tid >= 512 && tid < 640) sWpTail[tid - 512] = Wp[512 * 64 + (tid - 512)];
    for (int i = tid; i < RPB * TT; i += 1024) {
        int r = i / TT, tt = i - r * TT;
        sMask[i] = mask[(size_t)(b0 + r) * TT + tt];
        sHI[i]   = hist_item[(size_t)(b0 + r) * TT + tt];
        sHC[i]   = hist_cate[(size_t)(b0 + r) * TT + tt];
    }

    // ---- hoist weights: W[12] (role-unioned) + Wq[8] = 80 dwords ----
    float4 W[12];
    float4 Wq[8];
    if (isRZ) {
        int n0 = 2 * lane;                   // gate rows n0, n0+1 (0..127)
#pragma unroll
        for (int jc = 0; jc < 6; ++jc) {
            int c = c0A + 4 * jc;
#pragma unroll
            for (int ni = 0; ni < 2; ++ni)
                W[ni * 6 + jc] = (c < 128)
                    ? *(const float4*)(Wih + (n0 + ni) * 256 + 128 + c)
                    : *(const float4*)(Whh + (n0 + ni) * 64 + (c - 128));
        }
    } else {
        int nB = 128 + lane;                 // gate row 128..191 (n gate)
#pragma unroll
        for (int jc = 0; jc < 6; ++jc) {
            int c = c0A + 4 * jc;
            W[jc] = (c < 128)
                ? *(const float4*)(Wih + nB * 256 + 128 + c)
                : *(const float4*)(Whh + nB * 64 + (c - 128));
        }
    }
    // act col<128 boundary within the 24-col slice (wave-uniform)
    const int jcut = (sl <= 4) ? 6 : ((sl == 5) ? 2 : 0);
    // Wp slice: 1 row x 32 cols, register-stationary
    const int prow = tid & 511, sP = tid >> 9, c0P = 32 * sP;
    {
        const float4* wp0 = (const float4*)(Wp + prow * 64 + c0P);
#pragma unroll
        for (int q = 0; q < 8; ++q) Wq[q] = wp0[q];
    }

    int ts = seqlen[b0 + (wv & 7)] - 1;
    ts = ts < 0 ? 0 : (ts > TT - 1 ? TT - 1 : ts);
    __syncthreads();

    // ---- initial GI load (t = 0) into buffer 0, by n-waves ----
    if (!isRZ && lane < 48) {
        int ri = sHI[sl * TT], rc = sHC[sl * TT];
        float4 gi = *(const float4*)(GIi + (size_t)ri * GG + lane * 4);
        float4 gc = *(const float4*)(GIc + (size_t)rc * GG + lane * 4);
        *(float4*)&sGI2[sl * 192 + lane * 4] =
            make_float4(gi.x + gc.x, gi.y + gc.y, gi.z + gc.z, gi.w + gc.w);
    }

    for (int t = 0; t < TT; ++t) {
        // ---- phase 1 (+ GI prefetch for t+1 on n-waves, hidden under compute) ----
        if (isRZ) {
            float acc0[8], acc1[8];
#pragma unroll
            for (int r = 0; r < 8; ++r) { acc0[r] = 0.f; acc1[r] = 0.f; }
#pragma unroll
            for (int jc = 0; jc < 6; ++jc) {
#pragma unroll
                for (int r = 0; r < 8; ++r) {
                    float4 a = *(const float4*)&sAct[r * 192 + c0A + 4 * jc];
                    acc0[r] += dot4(W[jc], a);
                    acc1[r] += dot4(W[6 + jc], a);
                }
            }
#pragma unroll
            for (int r = 0; r < 8; ++r)
                *(float2*)&sU[sl * 1024 + r * 128 + 2 * lane] = make_float2(acc0[r], acc1[r]);
        } else {
            // issue prefetch first: loads in flight across the n-gate compute
            if (lane < 48) {
                int tn = (t + 1 < TT) ? t + 1 : TT - 1;
                int ri = sHI[sl * TT + tn], rc = sHC[sl * TT + tn];
                W[6] = *(const float4*)(GIi + (size_t)ri * GG + lane * 4);
                W[7] = *(const float4*)(GIc + (size_t)rc * GG + lane * 4);
            }
            float accR[8], accH[8];
#pragma unroll
            for (int r = 0; r < 8; ++r) { accR[r] = 0.f; accH[r] = 0.f; }
#pragma unroll
            for (int jc = 0; jc < 6; ++jc) {
                float d[8];
#pragma unroll
                for (int r = 0; r < 8; ++r)
                    d[r] = dot4(W[jc], *(const float4*)&sAct[r * 192 + c0A + 4 * jc]);
                if (jc < jcut) {            // wave-uniform branch, static acc index
#pragma unroll
                    for (int r = 0; r < 8; ++r) accR[r] += d[r];
                } else {
#pragma unroll
                    for (int r = 0; r < 8; ++r) accH[r] += d[r];
                }
            }
#pragma unroll
            for (int r = 0; r < 8; ++r) {
                sU[UNR + sl * 512 + r * 64 + lane] = accR[r];
                sU[UNH + sl * 512 + r * 64 + lane] = accH[r];
            }
            // commit GI for t+1
            if (lane < 48) {
                float4 gi = W[6], gc = W[7];
                *(float4*)&sGI2[((t + 1) & 1) * 1536 + sl * 192 + lane * 4] =
                    make_float4(gi.x + gc.x, gi.y + gc.y, gi.z + gc.z, gi.w + gc.w);
            }
        }
        __syncthreads();
        // ---- phase 2: GRU gates; commit h (waves 0-7, row = wave) ----
        if (isRZ) {
            const int r = sl;
            const float* gbuf = &sGI2[(t & 1) * 1536 + r * 192];
            float g_r = sBhh[lane] + gbuf[lane];
            float g_z = sBhh[64 + lane] + gbuf[64 + lane];
            float i_n = gbuf[128 + lane];
            float h_n = sBhh[128 + lane];
#pragma unroll
            for (int s = 0; s < 8; ++s) {
                g_r += sU[s * 1024 + r * 128 + lane];
                g_z += sU[s * 1024 + r * 128 + 64 + lane];
                i_n += sU[UNR + s * 512 + r * 64 + lane];
                h_n += sU[UNH + s * 512 + r * 64 + lane];
            }
            float rg = sigmf(g_r);
            float zg = sigmf(g_z);
            float ng = tanhf(i_n + rg * h_n);
            float h_old = sAct[r * 192 + 128 + lane];
            float hn = (1.f - zg) * ng + zg * h_old;
            float mt = sMask[r * TT + t];
            sHn[r * 64 + lane] = hn;
            sAct[r * 192 + 128 + lane] = (mt > 0.f) ? hn : h_old;
        }
        __syncthreads();
        // ---- phase 3: p partials = h_new @ Wp^T (all waves, Wq in regs) ----
        {
            float acc[8];
#pragma unroll
            for (int r = 0; r < 8; ++r) acc[r] = 0.f;
#pragma unroll
            for (int jc = 0; jc < 8; ++jc) {
                float4 w = Wq[jc];
#pragma unroll
                for (int r = 0; r < 8; ++r)
                    acc[r] += dot4(w, *(const float4*)&sHn[r * 64 + c0P + 4 * jc]);
            }
#pragma unroll
            for (int r = 0; r < 8; ++r)
                sU[sP * 4160 + r * 520 + prow] = acc[r];
        }
        if (tid < 4) {                        // tail Wp rows 512,513 (from LDS copy)
            int hrow = tid & 1, hs = tid >> 1;
            int c0 = 32 * hs;
            float a0[8];
#pragma unroll
            for (int r = 0; r < 8; ++r) a0[r] = 0.f;
#pragma unroll
            for (int jc = 0; jc < 8; ++jc) {
                float4 w0 = *(const float4*)&sWpTail[hrow * 64 + c0 + 4 * jc];
#pragma unroll
                for (int r = 0; r < 8; ++r)
                    a0[r] += dot4(w0, *(const float4*)&sHn[r * 64 + c0 + 4 * jc]);
            }
#pragma unroll
            for (int r = 0; r < 8; ++r)
                sU[hs * 4160 + r * 520 + 512 + hrow] = a0[r];
        }
        __syncthreads();
        // ---- phase 4: NTM addressing (waves 0-7, row = wave) ----
        if (isRZ) {
            const int row = sl;
            const int pb = row * 520;
#define PV(n) (sU[pb + (n)] + sU[4160 + pb + (n)] + sBp[(n)])
            float kr1 = tanhf(PV(lane)),       kr2 = tanhf(PV(64 + lane));
            float beta_r = softplusf(PV(128));
            float kw1 = tanhf(PV(129 + lane)), kw2 = tanhf(PV(193 + lane));
            float beta_w = softplusf(PV(257));
            float er1 = sigmf(PV(258 + lane)), er2 = sigmf(PV(322 + lane));
            float ad1 = tanhf(PV(386 + lane)), ad2 = tanhf(PV(450 + lane));
#undef PV
            float M1[4], M2[4];
#pragma unroll
            for (int s = 0; s < 4; ++s) {
                M1[s] = sM[row * 512 + s * 128 + lane];
                M2[s] = sM[row * 512 + s * 128 + 64 + lane];
            }
            float nkr = sqrtf(wred64(kr1 * kr1 + kr2 * kr2)) + 1e-8f;
            float nkw = sqrtf(wred64(kw1 * kw1 + kw2 * kw2)) + 1e-8f;
            float Kr[4], Kw[4];
#pragma unroll
            for (int s = 0; s < 4; ++s) {
                float nM = sqrtf(wred64(M1[s] * M1[s] + M2[s] * M2[s])) + 1e-8f;
                float dr = wred64(kr1 * M1[s] + kr2 * M2[s]);
                float dw = wred64(kw1 * M1[s] + kw2 * M2[s]);
                Kr[s] = dr / (nkr * nM);
                Kw[s] = dw / (nkw * nM);
            }
            float wr_[4], ww_[4];
            {
                float mx = fmaxf(fmaxf(beta_r * Kr[0], beta_r * Kr[1]),
                                 fmaxf(beta_r * Kr[2], beta_r * Kr[3]));
                float sum = 0.f;
#pragma unroll
                for (int s = 0; s < 4; ++s) { wr_[s] = expf(beta_r * Kr[s] - mx); sum += wr_[s]; }
                float inv = 1.f / sum;
#pragma unroll
                for (int s = 0; s < 4; ++s) wr_[s] *= inv;
            }
            {
                float mx = fmaxf(fmaxf(beta_w * Kw[0], beta_w * Kw[1]),
                                 fmaxf(beta_w * Kw[2], beta_w * Kw[3]));
                float sum = 0.f;
#pragma unroll
                for (int s = 0; s < 4; ++s) { ww_[s] = expf(beta_w * Kw[s] - mx); sum += ww_[s]; }
                float inv = 1.f / sum;
#pragma unroll
                for (int s = 0; s < 4; ++s) ww_[s] *= inv;
            }
            float rn1 = 0.f, rn2 = 0.f;
#pragma unroll
            for (int s = 0; s < 4; ++s) { rn1 += wr_[s] * M1[s]; rn2 += wr_[s] * M2[s]; }
            float mt = sMask[row * TT + t];
            bool vld = mt > 0.f;
            if (vld) {
#pragma unroll
                for (int s = 0; s < 4; ++s) {
                    sM[row * 512 + s * 128 + lane]      = M1[s] * (1.f - ww_[s] * er1) + ww_[s] * ad1;
                    sM[row * 512 + s * 128 + 64 + lane] = M2[s] * (1.f - ww_[s] * er2) + ww_[s] * ad2;
                }
                sAct[row * 192 + lane]      = rn1;   // committed read
                sAct[row * 192 + 64 + lane] = rn2;
            }
            if (t == ts) {
                // out = [h_new, read_new] @ Wo^T + bo  (unmasked values)
                // stash rn1/rn2 in the *current* GI buffer (free after phase 2)
                float* stash = &sGI2[(t & 1) * 1536 + row * 192];
                stash[lane] = rn1; stash[64 + lane] = rn2;
                __asm__ volatile("s_waitcnt lgkmcnt(0)" ::: "memory");
                float acc = bo[lane];
                const float* wo = Wo + lane * GG;
                for (int k = 0; k < 64; ++k)  acc += sHn[row * 64 + k] * wo[k];
                for (int k = 0; k < 128; ++k) acc += stash[k] * wo[64 + k];
                if (!vld) acc = 0.f;
                last_out[(size_t)(b0 + row) * 64 + lane] = acc;
            }
        }
        __syncthreads();
    }
}

// ---------------- K3: final MLP head --------------------------------------------
__global__ __launch_bounds__(128) void final_mlp(
    const int* __restrict__ item, const int* __restrict__ cate,
    const float* __restrict__ emb,
    const float* __restrict__ hist_sum, const float* __restrict__ last_out,
    const float* __restrict__ fc1w, const float* __restrict__ fc1b,
    const float* __restrict__ pa1,
    const float* __restrict__ fc2w, const float* __restrict__ fc2b,
    const float* __restrict__ pa2,
    const float* __restrict__ fc3w, const float* __restrict__ fc3b,
    float* __restrict__ out)
{
    __shared__ float sX[320], sH1[200], sH2[80];
    int b = blockIdx.x, tid = threadIdx.x;
    int it = item[b], ct = cate[b];
    for (int i = tid; i < 320; i += 128) {
        float val;
        if (i < 64)       val = emb[(size_t)it * 64 + i];
        else if (i < 128) val = emb[(size_t)ct * 64 + (i - 64)];
        else if (i < 256) val = hist_sum[(size_t)b * 128 + (i - 128)];
        else              val = last_out[(size_t)b * 64 + (i - 256)];
        sX[i] = val;
    }
    __syncthreads();
    float a1 = pa1[0];
    for (int o = tid; o < 200; o += 128) {
        const float4* w = (const float4*)(fc1w + o * 320);
        float acc = fc1b[o];
#pragma unroll
        for (int q = 0; q < 80; ++q) acc += dot4(w[q], *(const float4*)&sX[q * 4]);
        sH1[o] = acc > 0.f ? acc : a1 * acc;
    }
    __syncthreads();
    float a2 = pa2[0];
    for (int o = tid; o < 80; o += 128) {
        const float4* w = (const float4*)(fc2w + o * 200);
        float acc = fc2b[o];
#pragma unroll
        for (int q = 0; q < 50; ++q) acc += dot4(w[q], *(const float4*)&sH1[q * 4]);
        sH2[o] = acc > 0.f ? acc : a2 * acc;
    }
    __syncthreads();
    if (tid < 2) {
        const float4* w = (const float4*)(fc3w + tid * 80);
        float acc = fc3b[tid];
#pragma unroll
        for (int q = 0; q < 20; ++q) acc += dot4(w[q], *(const float4*)&sH2[q * 4]);
        out[b * 2 + tid] = acc;
    }
}

extern "C" void kernel_launch(void* const* d_in, const int* in_sizes, int n_in,
                              void* d_out, int out_size, void* d_ws, size_t ws_size,
                              hipStream_t stream) {
    (void)in_sizes; (void)n_in; (void)out_size; (void)ws_size;
    const int*   item      = (const int*)d_in[0];
    const int*   cate      = (const int*)d_in[1];
    const int*   hist_item = (const int*)d_in[2];
    const int*   hist_cate = (const int*)d_in[3];
    const float* mask = (const float*)d_in[4];
    const float* emb  = (const float*)d_in[5];
    const float* Wih  = (const float*)d_in[6];
    const float* Whh  = (const float*)d_in[7];
    const float* bih  = (const float*)d_in[8];
    const float* bhh  = (const float*)d_in[9];
    const float* Wp   = (const float*)d_in[10];
    const float* bp   = (const float*)d_in[11];
    const float* Wo   = (const float*)d_in[12];
    const float* bo   = (const float*)d_in[13];
    const float* M0   = (const float*)d_in[14];
    const float* fc1w = (const float*)d_in[15];
    const float* fc1b = (const float*)d_in[16];
    const float* pa1  = (const float*)d_in[17];
    const float* fc2w = (const float*)d_in[18];
    const float* fc2b = (const float*)d_in[19];
    const float* pa2  = (const float*)d_in[20];
    const float* fc3w = (const float*)d_in[21];
    const float* fc3b = (const float*)d_in[22];

    float* GIi = (float*)d_ws;                                   // V*192 f32
    float* GIc = GIi + (size_t)VV * GG;                          // V*192 f32
    float* hist_sum = GIc + (size_t)VV * GG;                     // B*128 f32
    float* last_out = hist_sum + (size_t)BB * 128;               // B*64 f32
    int* seqlen = (int*)(last_out + (size_t)BB * 64);            // B int

    build_tables<<<(VV + 63) / 64, 192, 0, stream>>>(emb, Wih, bih, GIi, GIc);
    hist_stats<<<BB, 128, 0, stream>>>(hist_item, hist_cate, mask, emb, hist_sum, seqlen);
    mimn_rnn<<<BB / RPB, 1024, 0, stream>>>(hist_item, hist_cate, mask, Wih, Whh, bhh,
                                            Wp, bp, Wo, bo, M0, GIi, GIc, seqlen, last_out);
    final_mlp<<<BB, 128, 0, stream>>>(item, cate, emb, hist_sum, last_out,
                                      fc1w, fc1b, pa1, fc2w, fc2b, pa2, fc3w, fc3b,
                                      (float*)d_out);
}